// Round 5
// baseline (163.727 us; speedup 1.0000x reference)
//
#include <hip/hip_runtime.h>
#include <cstdint>
#include <cstddef>

typedef __attribute__((ext_vector_type(8))) short short8;
typedef __attribute__((ext_vector_type(4))) float floatx4;
typedef __attribute__((ext_vector_type(16))) float floatx16;
typedef __attribute__((ext_vector_type(4))) short short4v;
typedef unsigned short u16;
typedef unsigned int u32;

#define B_   2
#define T_   2048
#define D_   1024
#define H_   16
#define HKV_ 4
#define HD_  64
#define KV_  256
#define M_   4096   // B*T
#define QS_  1536   // fused QKV row stride

#define NX   4194304
#define NWQ  1048576
#define NWK  262144
#define NWV  262144
#define NWP  1048576
#define NCAST (NX + NWQ + NWK + NWV + NWP)
#define CAST_BLOCKS (NCAST / 1024)
#define TAB_BLOCKS  256

__device__ __forceinline__ float b2f(u16 u) {
    union { u32 i; float f; } v; v.i = ((u32)u) << 16; return v.f;
}
__device__ __forceinline__ u16 f2b(float f) {
    union { float f; u32 i; } v; v.f = f;
    u32 r = v.i + 0x7FFF + ((v.i >> 16) & 1);
    return (u16)(r >> 16);
}

__device__ __forceinline__ void async16(const u16* g, u16* l) {
    __builtin_amdgcn_global_load_lds(
        (const __attribute__((address_space(1))) u32*)g,
        (__attribute__((address_space(3))) u32*)l, 16, 0, 0);
}

// v_cvt_pk_bf16_f32: dst.lo16 = bf16(lo), dst.hi16 = bf16(hi)  (RNE)
__device__ __forceinline__ u32 cvtpk(float lo, float hi) {
    u32 r;
    asm("v_cvt_pk_bf16_f32 %0, %1, %2" : "=v"(r) : "v"(lo), "v"(hi));
    return r;
}
// v_permlane32_swap_b32: a.hi-lanes <-> b.lo-lanes
__device__ __forceinline__ void swap32(u32& a, u32& b) {
    asm volatile("v_permlane32_swap_b32 %0, %1" : "+v"(a), "+v"(b));
}
__device__ __forceinline__ void swap32f(float& a, float& b) {
    asm volatile("v_permlane32_swap_b32 %0, %1" : "+v"(a), "+v"(b));
}
__device__ __forceinline__ short8 pkfrag(u32 w0, u32 w1, u32 w2, u32 w3) {
    union { u32 w[4]; short8 s; } u;
    u.w[0] = w0; u.w[1] = w1; u.w[2] = w2; u.w[3] = w3;
    return u.s;
}

// ---------------------------------------------------------------------------
// prep: all fp32->bf16 casts + RoPE cos/sin table.
// ---------------------------------------------------------------------------
__global__ __launch_bounds__(256) void prep(const float* __restrict__ x,
                                            const float* __restrict__ wq,
                                            const float* __restrict__ wk,
                                            const float* __restrict__ wv,
                                            const float* __restrict__ wp,
                                            u16* __restrict__ dst,
                                            float2* __restrict__ tab) {
    int blk = blockIdx.x;
    if (blk < CAST_BLOCKS) {
        int i = blk * 1024 + threadIdx.x * 4;
        const float* src; int off;
        if      (i < NX)                  { src = x;  off = i; }
        else if (i < NX+NWQ)              { src = wq; off = i - NX; }
        else if (i < NX+NWQ+NWK)          { src = wk; off = i - (NX+NWQ); }
        else if (i < NX+NWQ+NWK+NWV)      { src = wv; off = i - (NX+NWQ+NWK); }
        else                              { src = wp; off = i - (NX+NWQ+NWK+NWV); }
        float4 v = *(const float4*)(src + off);
        short4v o;
        o.x = (short)f2b(v.x); o.y = (short)f2b(v.y);
        o.z = (short)f2b(v.z); o.w = (short)f2b(v.w);
        *(short4v*)(dst + i) = o;
    } else {
        int idx = (blk - CAST_BLOCKS) * 256 + threadIdx.x;
        int t = idx >> 5, i = idx & 31;
        float freq = exp2f(-(float)i * (13.287712379549449f / 32.0f));
        float ang = (float)t * freq;
        tab[idx] = make_float2(cosf(ang), sinf(ang));
    }
}

// ---------------------------------------------------------------------------
// QKV GEMM: 128x64 tile, BK=64 as TWO BK=32 half-tiles per barrier.
// LDS XOR swizzle (both-sides) via pre-swizzled global source col.
// Fused epilogue: RMSNorm+RoPE+gain for Q/K cols, V transposed to Vt.
// ---------------------------------------------------------------------------
__global__ __launch_bounds__(256, 3) void gemm_qkv(const u16* __restrict__ A,
                                                   const u16* __restrict__ W,
                                                   u16* __restrict__ C,
                                                   u16* __restrict__ Vt,
                                                   const float* __restrict__ gain,
                                                   const float2* __restrict__ tab) {
    const int K = D_;
    __shared__ u16 As[2][2][128 * 32];
    __shared__ u16 Bs[2][2][64 * 32];
    const int t = threadIdx.x;
    const int wave = t >> 6, lane = t & 63;
    const int quad = lane >> 4, l16 = lane & 15;
    const int wm = wave * 32;
    const int m0 = blockIdx.y * 128, n0 = blockIdx.x * 64;

    floatx4 acc[2][4];
#pragma unroll
    for (int i = 0; i < 2; i++)
#pragma unroll
        for (int j = 0; j < 4; j++) acc[i][j] = (floatx4){0.f, 0.f, 0.f, 0.f};

    const int sr = t >> 2;
    const int sc = (((t & 3) ^ ((t >> 3) & 3)) * 8);   // pre-swizzled source col
    const u16* ga = A + (size_t)(m0 + sr) * K + sc;
    const u16* gb = W + (size_t)(n0 + sr) * K + sc;

    auto stage = [&](int buf, int half, int koff) {
        async16(ga + koff, As[buf][half] + t * 8);
        async16(ga + koff + (size_t)64 * K, As[buf][half] + t * 8 + 64 * 32);
        async16(gb + koff, Bs[buf][half] + t * 8);
    };

    stage(0, 0, 0);
    stage(0, 1, 32);

    int cur = 0;
    for (int kt = 0; kt < K; kt += 64) {
        __syncthreads();
        if (kt + 64 < K) {
            stage(cur ^ 1, 0, kt + 64);
            stage(cur ^ 1, 1, kt + 96);
        }
#pragma unroll
        for (int half = 0; half < 2; half++) {
            short8 af[2], bf[4];
#pragma unroll
            for (int mt = 0; mt < 2; mt++) {
                int row = wm + mt * 16 + l16;
                af[mt] = *(const short8*)(As[cur][half] + row * 32 +
                                          ((quad ^ ((row >> 1) & 3)) << 3));
            }
#pragma unroll
            for (int nt = 0; nt < 4; nt++) {
                int row = nt * 16 + l16;
                bf[nt] = *(const short8*)(Bs[cur][half] + row * 32 +
                                          ((quad ^ ((row >> 1) & 3)) << 3));
            }
#pragma unroll
            for (int mt = 0; mt < 2; mt++)
#pragma unroll
                for (int nt = 0; nt < 4; nt++)
                    acc[mt][nt] = __builtin_amdgcn_mfma_f32_16x16x32_bf16(
                        af[mt], bf[nt], acc[mt][nt], 0, 0, 0);
        }
        cur ^= 1;
    }

    const int col0 = n0;               // 64-aligned: exactly one head-block
    if (col0 < 1280) {
        float gs = (col0 < 1024)
                 ? gain[col0 >> 6] * (0.125f * 1.4426950408889634f)
                 : 1.0f;
#pragma unroll
        for (int mt = 0; mt < 2; mt++)
#pragma unroll
            for (int r = 0; r < 4; r++) {
                int row = m0 + wm + mt * 16 + quad * 4 + r;
                int tt = row & (T_ - 1);
                float v0 = acc[mt][0][r], v1 = acc[mt][1][r];
                float v2 = acc[mt][2][r], v3 = acc[mt][3][r];
                float ss = v0 * v0 + v1 * v1 + v2 * v2 + v3 * v3;
                ss += __shfl_xor(ss, 1); ss += __shfl_xor(ss, 2);
                ss += __shfl_xor(ss, 4); ss += __shfl_xor(ss, 8);
                float inv = rsqrtf(ss * (1.0f / 64.0f) + 1.1920929e-7f);
                v0 *= inv; v1 *= inv; v2 *= inv; v3 *= inv;
                float2 cs0 = tab[tt * 32 + l16];
                float2 cs1 = tab[tt * 32 + 16 + l16];
                float o0 = (v0 * cs0.x + v2 * cs0.y) * gs;
                float o1 = (v1 * cs1.x + v3 * cs1.y) * gs;
                float o2 = (v2 * cs0.x - v0 * cs0.y) * gs;
                float o3 = (v3 * cs1.x - v1 * cs1.y) * gs;
                u16* cp = C + (size_t)row * QS_ + col0 + l16;
                cp[0]  = f2b(o0);
                cp[16] = f2b(o1);
                cp[32] = f2b(o2);
                cp[48] = f2b(o3);
            }
    } else {
        const int g = (col0 - 1280) >> 6;
#pragma unroll
        for (int mt = 0; mt < 2; mt++)
#pragma unroll
            for (int r = 0; r < 4; r++) {
                int row = m0 + wm + mt * 16 + quad * 4 + r;
                int tt = row & (T_ - 1);
                int bb = row >> 11;
#pragma unroll
                for (int nt = 0; nt < 4; nt++)
                    Vt[(size_t)((bb * 4 + g) * 64 + nt * 16 + l16) * T_ + tt] =
                        f2b(acc[mt][nt][r]);
            }
    }
}

// ---------------------------------------------------------------------------
// Output-projection GEMM: 128x64 tile, BK=64 (two halves), swizzled LDS,
// plain fp32 stores.
// ---------------------------------------------------------------------------
__global__ __launch_bounds__(256, 3) void gemm_proj(const u16* __restrict__ A,
                                                    const u16* __restrict__ W,
                                                    float* __restrict__ C) {
    const int K = D_;
    __shared__ u16 As[2][2][128 * 32];
    __shared__ u16 Bs[2][2][64 * 32];
    const int t = threadIdx.x;
    const int wave = t >> 6, lane = t & 63;
    const int quad = lane >> 4, l16 = lane & 15;
    const int wm = wave * 32;
    const int m0 = blockIdx.y * 128, n0 = blockIdx.x * 64;

    floatx4 acc[2][4];
#pragma unroll
    for (int i = 0; i < 2; i++)
#pragma unroll
        for (int j = 0; j < 4; j++) acc[i][j] = (floatx4){0.f, 0.f, 0.f, 0.f};

    const int sr = t >> 2;
    const int sc = (((t & 3) ^ ((t >> 3) & 3)) * 8);
    const u16* ga = A + (size_t)(m0 + sr) * K + sc;
    const u16* gb = W + (size_t)(n0 + sr) * K + sc;

    auto stage = [&](int buf, int half, int koff) {
        async16(ga + koff, As[buf][half] + t * 8);
        async16(ga + koff + (size_t)64 * K, As[buf][half] + t * 8 + 64 * 32);
        async16(gb + koff, Bs[buf][half] + t * 8);
    };

    stage(0, 0, 0);
    stage(0, 1, 32);

    int cur = 0;
    for (int kt = 0; kt < K; kt += 64) {
        __syncthreads();
        if (kt + 64 < K) {
            stage(cur ^ 1, 0, kt + 64);
            stage(cur ^ 1, 1, kt + 96);
        }
#pragma unroll
        for (int half = 0; half < 2; half++) {
            short8 af[2], bf[4];
#pragma unroll
            for (int mt = 0; mt < 2; mt++) {
                int row = wm + mt * 16 + l16;
                af[mt] = *(const short8*)(As[cur][half] + row * 32 +
                                          ((quad ^ ((row >> 1) & 3)) << 3));
            }
#pragma unroll
            for (int nt = 0; nt < 4; nt++) {
                int row = nt * 16 + l16;
                bf[nt] = *(const short8*)(Bs[cur][half] + row * 32 +
                                          ((quad ^ ((row >> 1) & 3)) << 3));
            }
#pragma unroll
            for (int mt = 0; mt < 2; mt++)
#pragma unroll
                for (int nt = 0; nt < 4; nt++)
                    acc[mt][nt] = __builtin_amdgcn_mfma_f32_16x16x32_bf16(
                        af[mt], bf[nt], acc[mt][nt], 0, 0, 0);
        }
        cur ^= 1;
    }

#pragma unroll
    for (int mt = 0; mt < 2; mt++)
#pragma unroll
        for (int nt = 0; nt < 4; nt++)
#pragma unroll
            for (int r = 0; r < 4; r++) {
                int row = m0 + wm + mt * 16 + quad * 4 + r;
                int col = n0 + nt * 16 + l16;
                C[(size_t)row * D_ + col] = acc[mt][nt][r];
            }
}

// ---------------------------------------------------------------------------
// Flash attention (causal), 32x32x16 MFMA, in-register softmax.
// NO-SPLIT-K: block = 8 waves (512 thr) pairing q-tiles (u, 15-u) of 128
// rows each -> (2u+2)+(32-2u) = 34 key-tiles for EVERY block. Zero partial
// buffers, no combine kernel, every row scaled in-register and stored
// directly to Y. Wave = 32 q-rows x 32 keys (4 qw x 2 kw); per-segment
// kw-combine of acc/l via LDS (round-4's verified epilogue, qh removed).
// Triple-buffered K/V, counted vmcnt(2) (2 async16/thread/stage), one
// barrier per tile. Grid (8,16,2)=256 blocks = 1/CU (8 waves/CU, same
// wave occupancy as before). LDS 80KB.
// ---------------------------------------------------------------------------
__global__ __launch_bounds__(512, 1) void flash(const u16* __restrict__ QKV,
                                                const u16* __restrict__ Vtr,
                                                u16* __restrict__ Y) {
    const int u  = blockIdx.x;          // pair index [0,8)
    const int h  = blockIdx.y;
    const int b  = blockIdx.z;
    const int g  = h >> 2;
    const int t  = threadIdx.x;
    const int w    = t >> 6;            // wave [0,8)
    const int lane = t & 63;
    const int ln31 = lane & 31;
    const int hi   = lane >> 5;
    const int swz  = lane & 7;          // == row&7 for all row = *32+ln31
    const int qw   = w >> 1;            // q-quarter owner (32 rows)
    const int kw   = w & 1;             // key-half owner (32 keys)

    __shared__ u16 Kb[3][4096];
    __shared__ u16 Vb[3][4096];
    __shared__ float Ot[8192];          // 4 qw x (32q x 64d) f32

    // staging: 512 thr x (1 K + 1 V) async16 per tile; row = t>>3, XOR-seg
    const int srow = t >> 3;
    const int sseg = (t & 7) ^ (srow & 7);
    const u16* kgb = QKV + (size_t)(b * T_ + srow) * QS_ + D_ + g * 64 + sseg * 8;
    const u16* vgb = Vtr + (size_t)((b * 4 + g) * 64 + srow) * T_ + sseg * 8;

    auto stage = [&](int tile, int bi) {
        async16(kgb + (size_t)tile * 64 * QS_, &Kb[bi][t * 8]);
        async16(vgb + (size_t)tile * 64,       &Vb[bi][t * 8]);
    };
    const int n0 = 2 * u + 2;           // seg0 tile count
    auto tileOf = [&](int gidx) { return (gidx < n0) ? gidx : gidx - n0; };

    stage(tileOf(0), 0);
    stage(tileOf(1), 1);

    int gi = 0;
    for (int seg = 0; seg < 2; ++seg) {
        const int jt  = seg ? 15 - u : u;
        const int nIt = seg ? 32 - 2 * u : 2 * u + 2;
        const int qbase = jt * 128 + qw * 32;
        const int qrow  = qbase + ln31;

        const u16* qp = QKV + (size_t)(b * T_ + qrow) * QS_ + h * HD_;
        short8 aq[4];
#pragma unroll
        for (int kc = 0; kc < 4; kc++)
            aq[kc] = *(const short8*)(qp + kc * 16 + hi * 8);

        floatx16 acc[2];
#pragma unroll
        for (int dh = 0; dh < 2; dh++)
#pragma unroll
            for (int i = 0; i < 16; i++) acc[dh][i] = 0.f;
        float l = 0.f;

        for (int itn = 0; itn < nIt; ++itn, ++gi) {
            const int tk = tileOf(gi);
            // counted vmcnt: tile gi's 2 loads done; tile gi+1 stays in flight
            if (gi == 33) asm volatile("s_waitcnt vmcnt(0)" ::: "memory");
            else          asm volatile("s_waitcnt vmcnt(2)" ::: "memory");
            __builtin_amdgcn_s_barrier();
            asm volatile("" ::: "memory");

            const int bc = gi % 3;
            if (gi + 2 <= 33) stage(tileOf(gi + 2), (gi + 2) % 3);

            const u16* Kp = &Kb[bc][0];
            const u16* Vp = &Vb[bc][0];

            // K fragments: wave's 32-key slice x 64 d (4 reads)
            short8 kf[4];
#pragma unroll
            for (int kc = 0; kc < 4; kc++)
                kf[kc] = *(const short8*)(Kp + (kw * 32 + ln31) * 64 +
                                          (((kc * 2 + hi) ^ swz) << 3));

            floatx16 s2;
#pragma unroll
            for (int i = 0; i < 16; i++) s2[i] = 0.f;

            __builtin_amdgcn_s_setprio(1);
#pragma unroll
            for (int kc = 0; kc < 4; kc++)
                s2 = __builtin_amdgcn_mfma_f32_32x32x16_bf16(kf[kc], aq[kc], s2, 0, 0, 0);
            __builtin_amdgcn_s_setprio(0);

            // V fragments: 64 d x wave's 32-key slice (4 reads)
            short8 vfr[2][2];
#pragma unroll
            for (int dh = 0; dh < 2; dh++)
#pragma unroll
                for (int kc2 = 0; kc2 < 2; kc2++)
                    vfr[dh][kc2] = *(const short8*)(Vp + (dh * 32 + ln31) * 64 +
                                        (((kw * 4 + kc2 * 2 + hi) ^ swz) << 3));

            // softmax: exp2 (+ causal mask on diagonal tiles), pack to bf16
            u32 pw[8];
            if (tk >= 2 * jt) {
#pragma unroll
                for (int i = 0; i < 8; i++) {
                    int key0 = tk * 64 + kw * 32 +
                               ((2 * i) & 3) + (((2 * i) >> 2) << 3) + (hi << 2);
                    float e0 = __builtin_amdgcn_exp2f(s2[2 * i]);
                    float e1 = __builtin_amdgcn_exp2f(s2[2 * i + 1]);
                    e0 = (key0 <= qrow) ? e0 : 0.f;
                    e1 = (key0 + 1 <= qrow) ? e1 : 0.f;
                    l += e0 + e1;
                    pw[i] = cvtpk(e0, e1);
                }
            } else {
#pragma unroll
                for (int i = 0; i < 8; i++) {
                    float e0 = __builtin_amdgcn_exp2f(s2[2 * i]);
                    float e1 = __builtin_amdgcn_exp2f(s2[2 * i + 1]);
                    l += e0 + e1;
                    pw[i] = cvtpk(e0, e1);
                }
            }

            // in-register P -> bf16 B-fragments (keys become k-dim)
            u32 a0 = pw[0], c0 = pw[1], b0 = pw[2], d0 = pw[3];
            swap32(a0, b0); swap32(c0, d0);
            short8 pb0 = pkfrag(a0, c0, b0, d0);
            u32 a1 = pw[4], c1 = pw[5], b1 = pw[6], d1 = pw[7];
            swap32(a1, b1); swap32(c1, d1);
            short8 pb1 = pkfrag(a1, c1, b1, d1);

            __builtin_amdgcn_s_setprio(1);
            acc[0] = __builtin_amdgcn_mfma_f32_32x32x16_bf16(vfr[0][0], pb0, acc[0], 0, 0, 0);
            acc[1] = __builtin_amdgcn_mfma_f32_32x32x16_bf16(vfr[1][0], pb0, acc[1], 0, 0, 0);
            acc[0] = __builtin_amdgcn_mfma_f32_32x32x16_bf16(vfr[0][1], pb1, acc[0], 0, 0, 0);
            acc[1] = __builtin_amdgcn_mfma_f32_32x32x16_bf16(vfr[1][1], pb1, acc[1], 0, 0, 0);
            __builtin_amdgcn_s_setprio(0);
        }

        // ---- segment epilogue: kw-combine, scale, transpose, store ----
        float la = l, lb = l;
        swap32f(la, lb);                 // combine hi/lo key-quarter sums
        float lt = la + lb;              // this wave's 32-key partial sum

        const int fb = (gi + 2) % 3;     // free K/V buffer (tile gi-1's)
        float* Lsh = (float*)&Vb[fb][0]; // 128 f32 scratch for l exchange
        float* otq = Ot + qw * 2048;     // this qw-group's 32q x 64d region

        __builtin_amdgcn_s_barrier();    // all waves done reading tile LDS
        asm volatile("" ::: "memory");

        if (kw == 1) {                   // partner writes transposed partial
#pragma unroll
            for (int dh = 0; dh < 2; dh++)
#pragma unroll
                for (int g4 = 0; g4 < 4; g4++) {
                    int ss = (dh * 8 + g4 * 2 + hi) ^ (ln31 & 7);
                    float4 v = make_float4(acc[dh][g4 * 4 + 0],
                                           acc[dh][g4 * 4 + 1],
                                           acc[dh][g4 * 4 + 2],
                                           acc[dh][g4 * 4 + 3]);
                    *(float4*)(otq + ln31 * 64 + ss * 4) = v;
                }
            if (hi == 0) Lsh[qw * 32 + ln31] = lt;
        }
        asm volatile("s_waitcnt lgkmcnt(0)" ::: "memory");
        __builtin_amdgcn_s_barrier();
        asm volatile("" ::: "memory");

        if (kw == 0) {                   // owner adds, scales, writes back
            float ltot = lt + Lsh[qw * 32 + ln31];
            float inv = 1.0f / ltot;
#pragma unroll
            for (int dh = 0; dh < 2; dh++)
#pragma unroll
                for (int g4 = 0; g4 < 4; g4++) {
                    int ss = (dh * 8 + g4 * 2 + hi) ^ (ln31 & 7);
                    float4 v = *(const float4*)(otq + ln31 * 64 + ss * 4);
                    float4 o;
                    o.x = (acc[dh][g4 * 4 + 0] + v.x) * inv;
                    o.y = (acc[dh][g4 * 4 + 1] + v.y) * inv;
                    o.z = (acc[dh][g4 * 4 + 2] + v.z) * inv;
                    o.w = (acc[dh][g4 * 4 + 3] + v.w) * inv;
                    *(float4*)(otq + ln31 * 64 + ss * 4) = o;
                }
        }
        asm volatile("s_waitcnt lgkmcnt(0)" ::: "memory");
        __builtin_amdgcn_s_barrier();
        asm volatile("" ::: "memory");

        // all-wave coalesced store: wave w handles q-rows w*16..w*16+15
        const int hq = lane >> 4;
        const int s4 = lane & 15;
        u16* ybase = Y + (size_t)(b * T_ + jt * 128) * D_ + h * HD_;
#pragma unroll
        for (int it = 0; it < 4; it++) {
            int q128 = w * 16 + it * 4 + hq;
            int ql = q128 & 31, rg = q128 >> 5;
            int ss = s4 ^ (ql & 7);
            float4 v = *(const float4*)(Ot + rg * 2048 + ql * 64 + ss * 4);
            uint2 yw;
            yw.x = cvtpk(v.x, v.y);
            yw.y = cvtpk(v.z, v.w);
            *(uint2*)(ybase + (size_t)q128 * D_ + s4 * 4) = yw;
        }
    }
}

// ---------------------------------------------------------------------------
extern "C" void kernel_launch(void* const* d_in, const int* in_sizes, int n_in,
                              void* d_out, int out_size, void* d_ws, size_t ws_size,
                              hipStream_t stream) {
    const float* x    = (const float*)d_in[0];
    const float* Wq   = (const float*)d_in[1];
    const float* Wk   = (const float*)d_in[2];
    const float* Wv   = (const float*)d_in[3];
    const float* Wp   = (const float*)d_in[4];
    const float* gain = (const float*)d_in[5];
    float* out = (float*)d_out;

    u16* xb   = (u16*)d_ws;
    u16* Wcat = xb + (size_t)NX;
    u16* Wpb  = Wcat + (size_t)(NWQ + NWK + NWV);
    u16* QKV  = Wpb + (size_t)NWP;
    u16* Vt   = QKV + (size_t)M_ * QS_;
    u16* Y    = Vt + (size_t)M_ * KV_;
    float2* tab = (float2*)(Y + (size_t)M_ * D_);          // 65536 float2

    prep<<<CAST_BLOCKS + TAB_BLOCKS, 256, 0, stream>>>(x, Wq, Wk, Wv, Wp, xb, tab);

    gemm_qkv<<<dim3(QS_ / 64, M_ / 128), 256, 0, stream>>>(xb, Wcat, QKV, Vt,
                                                           gain, tab);

    flash<<<dim3(8, H_, B_), 512, 0, stream>>>(QKV, Vt, Y);

    gemm_proj<<<dim3(D_ / 64, M_ / 128), 256, 0, stream>>>(Y, Wpb, out);
}

// Round 8
// 159.936 us; speedup vs baseline: 1.0237x; 1.0237x over previous
//
#include <hip/hip_runtime.h>
#include <cstdint>
#include <cstddef>

typedef __attribute__((ext_vector_type(8))) short short8;
typedef __attribute__((ext_vector_type(4))) float floatx4;
typedef __attribute__((ext_vector_type(4))) short short4v;
typedef unsigned short u16;
typedef unsigned int u32;

#define B_   2
#define T_   2048
#define D_   1024
#define H_   16
#define HKV_ 4
#define HD_  64
#define KV_  256
#define M_   4096   // B*T
#define QS_  1536   // fused QKV row stride

#define NX   4194304
#define NWQ  1048576
#define NWK  262144
#define NWV  262144
#define NWP  1048576
#define NCAST (NX + NWQ + NWK + NWV + NWP)
#define CAST_BLOCKS (NCAST / 1024)
#define TAB_BLOCKS  256

__device__ __forceinline__ float b2f(u16 u) {
    union { u32 i; float f; } v; v.i = ((u32)u) << 16; return v.f;
}
__device__ __forceinline__ u16 f2b(float f) {
    union { float f; u32 i; } v; v.f = f;
    u32 r = v.i + 0x7FFF + ((v.i >> 16) & 1);
    return (u16)(r >> 16);
}
__device__ __forceinline__ u32 pack_hi(float a, float b) {
    union { float f; u32 u; } ua, ub; ua.f = a; ub.f = b;
    return (ua.u >> 16) | (ub.u & 0xFFFF0000u);
}

__device__ __forceinline__ void async16(const u16* g, u16* l) {
    __builtin_amdgcn_global_load_lds(
        (const __attribute__((address_space(1))) u32*)g,
        (__attribute__((address_space(3))) u32*)l, 16, 0, 0);
}

// ---------------------------------------------------------------------------
// prep: all fp32->bf16 casts + RoPE cos/sin table.
// ---------------------------------------------------------------------------
__global__ __launch_bounds__(256) void prep(const float* __restrict__ x,
                                            const float* __restrict__ wq,
                                            const float* __restrict__ wk,
                                            const float* __restrict__ wv,
                                            const float* __restrict__ wp,
                                            u16* __restrict__ dst,
                                            float2* __restrict__ tab) {
    int blk = blockIdx.x;
    if (blk < CAST_BLOCKS) {
        int i = blk * 1024 + threadIdx.x * 4;
        const float* src; int off;
        if      (i < NX)                  { src = x;  off = i; }
        else if (i < NX+NWQ)              { src = wq; off = i - NX; }
        else if (i < NX+NWQ+NWK)          { src = wk; off = i - (NX+NWQ); }
        else if (i < NX+NWQ+NWK+NWV)      { src = wv; off = i - (NX+NWQ+NWK); }
        else                              { src = wp; off = i - (NX+NWQ+NWK+NWV); }
        float4 v = *(const float4*)(src + off);
        short4v o;
        o.x = (short)f2b(v.x); o.y = (short)f2b(v.y);
        o.z = (short)f2b(v.z); o.w = (short)f2b(v.w);
        *(short4v*)(dst + i) = o;
    } else {
        int idx = (blk - CAST_BLOCKS) * 256 + threadIdx.x;
        int t = idx >> 5, i = idx & 31;
        float freq = exp2f(-(float)i * (13.287712379549449f / 32.0f));
        float ang = (float)t * freq;
        tab[idx] = make_float2(cosf(ang), sinf(ang));
    }
}

// ---------------------------------------------------------------------------
// QKV GEMM: 128x128 tile (m97-class), BK=64 as two BK=32 halves per barrier.
// Waves 2x2; each wave owns a 64x64 quadrant: 8 ds_read_b128 + 16 MFMA per
// half (2.0 MFMA/read vs 1.33 at 128x64). Each wave's 64 output cols are one
// 64-aligned head-block -> round-0's verified RMSNorm+RoPE / Vt epilogues
// apply verbatim with col0 = n0 + wc*64. LDS 64KB -> 2 blocks/CU.
// ---------------------------------------------------------------------------
__global__ __launch_bounds__(256, 2) void gemm_qkv(const u16* __restrict__ A,
                                                   const u16* __restrict__ W,
                                                   u16* __restrict__ C,
                                                   u16* __restrict__ Vt,
                                                   const float* __restrict__ gain,
                                                   const float2* __restrict__ tab) {
    const int K = D_;
    __shared__ u16 As[2][2][128 * 32];
    __shared__ u16 Bs[2][2][128 * 32];
    const int t = threadIdx.x;
    const int wave = t >> 6, lane = t & 63;
    const int quad = lane >> 4, l16 = lane & 15;
    const int wr = (wave >> 1) * 64, wc = (wave & 1) * 64;
    const int m0 = blockIdx.y * 128, n0 = blockIdx.x * 128;

    floatx4 acc[4][4];
#pragma unroll
    for (int i = 0; i < 4; i++)
#pragma unroll
        for (int j = 0; j < 4; j++) acc[i][j] = (floatx4){0.f, 0.f, 0.f, 0.f};

    const int sr = t >> 2;
    const int sc = (((t & 3) ^ ((t >> 3) & 3)) * 8);   // pre-swizzled source col
    const u16* ga = A + (size_t)(m0 + sr) * K + sc;
    const u16* gb = W + (size_t)(n0 + sr) * K + sc;

    auto stage = [&](int buf, int half, int koff) {
        async16(ga + koff, As[buf][half] + t * 8);
        async16(ga + koff + (size_t)64 * K, As[buf][half] + t * 8 + 2048);
        async16(gb + koff, Bs[buf][half] + t * 8);
        async16(gb + koff + (size_t)64 * K, Bs[buf][half] + t * 8 + 2048);
    };

    stage(0, 0, 0);
    stage(0, 1, 32);

    int cur = 0;
    for (int kt = 0; kt < K; kt += 64) {
        __syncthreads();
        if (kt + 64 < K) {
            stage(cur ^ 1, 0, kt + 64);
            stage(cur ^ 1, 1, kt + 96);
        }
#pragma unroll
        for (int half = 0; half < 2; half++) {
            short8 af[4], bf[4];
#pragma unroll
            for (int mt = 0; mt < 4; mt++) {
                int row = wr + mt * 16 + l16;
                af[mt] = *(const short8*)(As[cur][half] + row * 32 +
                                          ((quad ^ ((row >> 1) & 3)) << 3));
            }
#pragma unroll
            for (int nt = 0; nt < 4; nt++) {
                int row = wc + nt * 16 + l16;
                bf[nt] = *(const short8*)(Bs[cur][half] + row * 32 +
                                          ((quad ^ ((row >> 1) & 3)) << 3));
            }
#pragma unroll
            for (int mt = 0; mt < 4; mt++)
#pragma unroll
                for (int nt = 0; nt < 4; nt++)
                    acc[mt][nt] = __builtin_amdgcn_mfma_f32_16x16x32_bf16(
                        af[mt], bf[nt], acc[mt][nt], 0, 0, 0);
        }
        cur ^= 1;
    }

    const int col0 = n0 + wc;          // 64-aligned: exactly one head-block
    if (col0 < 1280) {
        float gs = (col0 < 1024)
                 ? gain[col0 >> 6] * (0.125f * 1.4426950408889634f)
                 : 1.0f;
#pragma unroll
        for (int mt = 0; mt < 4; mt++)
#pragma unroll
            for (int r = 0; r < 4; r++) {
                int row = m0 + wr + mt * 16 + quad * 4 + r;
                int tt = row & (T_ - 1);
                float v0 = acc[mt][0][r], v1 = acc[mt][1][r];
                float v2 = acc[mt][2][r], v3 = acc[mt][3][r];
                float ss = v0 * v0 + v1 * v1 + v2 * v2 + v3 * v3;
                ss += __shfl_xor(ss, 1); ss += __shfl_xor(ss, 2);
                ss += __shfl_xor(ss, 4); ss += __shfl_xor(ss, 8);
                float inv = rsqrtf(ss * (1.0f / 64.0f) + 1.1920929e-7f);
                v0 *= inv; v1 *= inv; v2 *= inv; v3 *= inv;
                float2 cs0 = tab[tt * 32 + l16];
                float2 cs1 = tab[tt * 32 + 16 + l16];
                float o0 = (v0 * cs0.x + v2 * cs0.y) * gs;
                float o1 = (v1 * cs1.x + v3 * cs1.y) * gs;
                float o2 = (v2 * cs0.x - v0 * cs0.y) * gs;
                float o3 = (v3 * cs1.x - v1 * cs1.y) * gs;
                u16* cp = C + (size_t)row * QS_ + col0 + l16;
                cp[0]  = f2b(o0);
                cp[16] = f2b(o1);
                cp[32] = f2b(o2);
                cp[48] = f2b(o3);
            }
    } else {
        const int g = (col0 - 1280) >> 6;
#pragma unroll
        for (int mt = 0; mt < 4; mt++)
#pragma unroll
            for (int r = 0; r < 4; r++) {
                int row = m0 + wr + mt * 16 + quad * 4 + r;
                int tt = row & (T_ - 1);
                int bb = row >> 11;
#pragma unroll
                for (int nt = 0; nt < 4; nt++)
                    Vt[(size_t)((bb * 4 + g) * 64 + nt * 16 + l16) * T_ + tt] =
                        f2b(acc[mt][nt][r]);
            }
    }
}

// ---------------------------------------------------------------------------
// Output-projection GEMM: 128x128 tile, BK=64 (two halves), swizzled LDS,
// plain fp32 stores.
// ---------------------------------------------------------------------------
__global__ __launch_bounds__(256, 2) void gemm_proj(const u16* __restrict__ A,
                                                    const u16* __restrict__ W,
                                                    float* __restrict__ C) {
    const int K = D_;
    __shared__ u16 As[2][2][128 * 32];
    __shared__ u16 Bs[2][2][128 * 32];
    const int t = threadIdx.x;
    const int wave = t >> 6, lane = t & 63;
    const int quad = lane >> 4, l16 = lane & 15;
    const int wr = (wave >> 1) * 64, wc = (wave & 1) * 64;
    const int m0 = blockIdx.y * 128, n0 = blockIdx.x * 128;

    floatx4 acc[4][4];
#pragma unroll
    for (int i = 0; i < 4; i++)
#pragma unroll
        for (int j = 0; j < 4; j++) acc[i][j] = (floatx4){0.f, 0.f, 0.f, 0.f};

    const int sr = t >> 2;
    const int sc = (((t & 3) ^ ((t >> 3) & 3)) * 8);
    const u16* ga = A + (size_t)(m0 + sr) * K + sc;
    const u16* gb = W + (size_t)(n0 + sr) * K + sc;

    auto stage = [&](int buf, int half, int koff) {
        async16(ga + koff, As[buf][half] + t * 8);
        async16(ga + koff + (size_t)64 * K, As[buf][half] + t * 8 + 2048);
        async16(gb + koff, Bs[buf][half] + t * 8);
        async16(gb + koff + (size_t)64 * K, Bs[buf][half] + t * 8 + 2048);
    };

    stage(0, 0, 0);
    stage(0, 1, 32);

    int cur = 0;
    for (int kt = 0; kt < K; kt += 64) {
        __syncthreads();
        if (kt + 64 < K) {
            stage(cur ^ 1, 0, kt + 64);
            stage(cur ^ 1, 1, kt + 96);
        }
#pragma unroll
        for (int half = 0; half < 2; half++) {
            short8 af[4], bf[4];
#pragma unroll
            for (int mt = 0; mt < 4; mt++) {
                int row = wr + mt * 16 + l16;
                af[mt] = *(const short8*)(As[cur][half] + row * 32 +
                                          ((quad ^ ((row >> 1) & 3)) << 3));
            }
#pragma unroll
            for (int nt = 0; nt < 4; nt++) {
                int row = wc + nt * 16 + l16;
                bf[nt] = *(const short8*)(Bs[cur][half] + row * 32 +
                                          ((quad ^ ((row >> 1) & 3)) << 3));
            }
#pragma unroll
            for (int mt = 0; mt < 4; mt++)
#pragma unroll
                for (int nt = 0; nt < 4; nt++)
                    acc[mt][nt] = __builtin_amdgcn_mfma_f32_16x16x32_bf16(
                        af[mt], bf[nt], acc[mt][nt], 0, 0, 0);
        }
        cur ^= 1;
    }

#pragma unroll
    for (int mt = 0; mt < 4; mt++)
#pragma unroll
        for (int nt = 0; nt < 4; nt++)
#pragma unroll
            for (int r = 0; r < 4; r++) {
                int row = m0 + wr + mt * 16 + quad * 4 + r;
                int col = n0 + wc + nt * 16 + l16;
                C[(size_t)row * D_ + col] = acc[mt][nt][r];
            }
}

// ---------------------------------------------------------------------------
// Flash attention (causal), no-max softmax, SPLIT-K with DEDICATED partial
// buffers (no atomics, no pre-zeroing). Grid (32,16,2) = 1024 blocks = 4/CU.
//  u<16 : seg0 = q-tile xp, keys [0,xp+1) (complete -> direct Y);
//          seg1 = q-tile 31-xp, keys [16,32-xp) -> partial buffer 0.
//  u>=16: q-tile 31-(u&15), keys [0,16) -> partial buffer 1.
// (Byte-identical to the round-0 PASSED kernel.)
// ---------------------------------------------------------------------------
__global__ __launch_bounds__(256, 4) void flash(const u16* __restrict__ QKV,
                                                const u16* __restrict__ Vtr,
                                                u16* __restrict__ Y,
                                                float* __restrict__ Opart,
                                                float* __restrict__ Lpart) {
    const int u  = blockIdx.x;
    const int h  = blockIdx.y;
    const int b  = blockIdx.z;
    const int g  = h >> 2;
    const int w    = threadIdx.x >> 6;
    const int lane = threadIdx.x & 63;
    const int quad = lane >> 4, l16 = lane & 15;

    __shared__ u16 Kt[64 * 64];
    __shared__ u16 Vs[64 * 64];
    __shared__ __align__(16) u16 P[4][16][72];

    const int xp = u & 15;
    const int nseg = (u < 16) ? 2 : 1;
    const int buf  = (u < 16) ? 0 : 1;
    int m0s[2], k0s[2], k1s[2];
    if (u < 16) {
        m0s[0] = xp * 64;        k0s[0] = 0;  k1s[0] = xp + 1;
        m0s[1] = (31 - xp) * 64; k0s[1] = 16; k1s[1] = 32 - xp;
    } else {
        m0s[0] = (31 - xp) * 64; k0s[0] = 0;  k1s[0] = 16;
        m0s[1] = 0; k0s[1] = 0; k1s[1] = 0;
    }

    const int srow = w * 16 + (lane >> 3);
    const int sseg = (lane & 7) ^ ((lane >> 3) & 7);
    const u16* kgb = QKV + (size_t)(b * T_ + srow) * QS_ + D_ + g * 64 + sseg * 8;
    const u16* vgb = Vtr + (size_t)((b * 4 + g) * 64 + srow) * T_ + sseg * 8;
    u16* klds = Kt + w * 1024 + lane * 8;
    u16* vlds = Vs + w * 1024 + lane * 8;
    const int sw0 = (quad ^ (l16 & 7)) * 8;
    const int sw1 = ((4 + quad) ^ (l16 & 7)) * 8;

    auto stage = [&](int tile) {
        const u16* kg = kgb + (size_t)tile * 64 * QS_;
        const u16* vg = vgb + (size_t)tile * 64;
        async16(kg, klds);
        async16(kg + (size_t)8 * QS_, klds + 512);
        async16(vg, vlds);
        async16(vg + (size_t)8 * T_, vlds + 512);
    };

    short8 ones;
#pragma unroll
    for (int i = 0; i < 8; i++) ones[i] = (short)0x3F80;  // bf16 1.0

    stage(k0s[0]);

    for (int seg = 0; seg < nseg; ++seg) {
        const int mseg = m0s[seg], k0 = k0s[seg], k1 = k1s[seg];
        const int jt = mseg >> 6;         // masked tile index (== q-tile idx)
        const int m = mseg + w * 16;

        const u16* qp = QKV + (size_t)(b * T_ + m + l16) * QS_ + h * HD_ + quad * 8;
        short8 aq0 = *(const short8*)(qp);
        short8 aq1 = *(const short8*)(qp + 32);

        floatx4 acc[4];
#pragma unroll
        for (int i = 0; i < 4; i++) acc[i] = (floatx4){0.f, 0.f, 0.f, 0.f};
        floatx4 lAcc = (floatx4){0.f, 0.f, 0.f, 0.f};

        for (int tk = k0; tk < k1; ++tk) {
            __syncthreads();              // tile tk staged

            floatx4 S[4];
#pragma unroll
            for (int nt = 0; nt < 4; nt++) {
                const u16* kr = Kt + (nt * 16 + l16) * 64;
                short8 kf0 = *(const short8*)(kr + sw0);
                short8 kf1 = *(const short8*)(kr + sw1);
                S[nt] = (floatx4){0.f, 0.f, 0.f, 0.f};
                S[nt] = __builtin_amdgcn_mfma_f32_16x16x32_bf16(kf0, aq0, S[nt], 0, 0, 0);
                S[nt] = __builtin_amdgcn_mfma_f32_16x16x32_bf16(kf1, aq1, S[nt], 0, 0, 0);
            }
            short8 vf[4][2];
#pragma unroll
            for (int dd = 0; dd < 4; dd++) {
                const u16* vr = Vs + (dd * 16 + l16) * 64;
                vf[dd][0] = *(const short8*)(vr + sw0);
                vf[dd][1] = *(const short8*)(vr + sw1);
            }
            __syncthreads();              // all waves done with K/V LDS

            int nxt = (tk + 1 < k1) ? tk + 1 : ((seg + 1 < nseg) ? k0s[seg + 1] : -1);
            if (nxt >= 0) stage(nxt);

            const bool msk = (tk == jt);
            const int qq = m + l16;
#pragma unroll
            for (int nt = 0; nt < 4; nt++) {
                float p[4];
#pragma unroll
                for (int r = 0; r < 4; r++) {
                    float e = __builtin_amdgcn_exp2f(S[nt][r]);
                    if (msk) {
                        int key = tk * 64 + nt * 16 + quad * 4 + r;
                        e = (key <= qq) ? e : 0.f;
                    }
                    p[r] = e;
                }
                uint2 pw; pw.x = pack_hi(p[0], p[1]); pw.y = pack_hi(p[2], p[3]);
                *(uint2*)&P[w][l16][nt * 16 + quad * 4] = pw;
            }
            short8 pf0 = *(const short8*)&P[w][l16][quad * 8];
            short8 pf1 = *(const short8*)&P[w][l16][quad * 8 + 32];
#pragma unroll
            for (int dd = 0; dd < 4; dd++) {
                acc[dd] = __builtin_amdgcn_mfma_f32_16x16x32_bf16(pf0, vf[dd][0], acc[dd], 0, 0, 0);
                acc[dd] = __builtin_amdgcn_mfma_f32_16x16x32_bf16(pf1, vf[dd][1], acc[dd], 0, 0, 0);
            }
            lAcc = __builtin_amdgcn_mfma_f32_16x16x32_bf16(pf0, ones, lAcc, 0, 0, 0);
            lAcc = __builtin_amdgcn_mfma_f32_16x16x32_bf16(pf1, ones, lAcc, 0, 0, 0);
        }

        if (u < 16 && seg == 0) {
#pragma unroll
            for (int r = 0; r < 4; r++) {
                float inv = 1.0f / lAcc[r];
                int row = m + quad * 4 + r;
                u16* yp = Y + (size_t)(b * T_ + row) * D_ + h * HD_ + l16;
#pragma unroll
                for (int dd = 0; dd < 4; dd++)
                    yp[dd * 16] = f2b(acc[dd][r] * inv);
            }
        } else {
#pragma unroll
            for (int r = 0; r < 4; r++) {
                int rp = m + quad * 4 + r - 1024;
                float* op = Opart + ((size_t)((buf * 2 + b) * 1024 + rp)) * 1024
                          + h * HD_ + l16;
#pragma unroll
                for (int dd = 0; dd < 4; dd++)
                    op[dd * 16] = acc[dd][r];
                if (l16 == 0)
                    Lpart[((buf * 2 + b) * 1024 + rp) * 16 + h] = lAcc[r];
            }
        }
    }
}

// ---------------------------------------------------------------------------
// combine: Y[rows 1024..2047 per b] = (O0+O1) / (l0+l1)
// ---------------------------------------------------------------------------
__global__ __launch_bounds__(256) void combine(const float* __restrict__ Opart,
                                               const float* __restrict__ Lpart,
                                               u16* __restrict__ Y) {
    int e = (blockIdx.x * 256 + threadIdx.x) * 4;   // < 2*1024*1024
    int b = e >> 20;
    int rem = e & 1048575;
    int row = rem >> 10, col = rem & 1023;
    int li = (b * 1024 + row) * 16 + (col >> 6);
    float l0 = Lpart[li];
    float l1 = Lpart[li + 2 * 1024 * 16];
    float inv = 1.0f / (l0 + l1);
    size_t oi = ((size_t)(b * 1024 + row)) * 1024 + col;
    float4 o0 = *(const float4*)(Opart + oi);
    float4 o1 = *(const float4*)(Opart + oi + (size_t)2 * 1024 * 1024);
    short4v y;
    y.x = (short)f2b((o0.x + o1.x) * inv); y.y = (short)f2b((o0.y + o1.y) * inv);
    y.z = (short)f2b((o0.z + o1.z) * inv); y.w = (short)f2b((o0.w + o1.w) * inv);
    *(short4v*)(Y + (size_t)(b * T_ + 1024 + row) * D_ + col) = y;
}

// ---------------------------------------------------------------------------
extern "C" void kernel_launch(void* const* d_in, const int* in_sizes, int n_in,
                              void* d_out, int out_size, void* d_ws, size_t ws_size,
                              hipStream_t stream) {
    const float* x    = (const float*)d_in[0];
    const float* Wq   = (const float*)d_in[1];
    const float* Wk   = (const float*)d_in[2];
    const float* Wv   = (const float*)d_in[3];
    const float* Wp   = (const float*)d_in[4];
    const float* gain = (const float*)d_in[5];
    float* out = (float*)d_out;

    u16* xb   = (u16*)d_ws;
    u16* Wcat = xb + (size_t)NX;
    u16* Wpb  = Wcat + (size_t)(NWQ + NWK + NWV);
    u16* QKV  = Wpb + (size_t)NWP;
    u16* Vt   = QKV + (size_t)M_ * QS_;
    u16* Y    = Vt + (size_t)M_ * KV_;
    float2* tab = (float2*)(Y + (size_t)M_ * D_);          // 65536 float2
    float* Opart = (float*)(tab + 65536);                  // 2buf*2b*1024*1024 f32
    float* Lpart = Opart + (size_t)4 * 1024 * 1024;        // 2buf*2b*1024*16 f32

    prep<<<CAST_BLOCKS + TAB_BLOCKS, 256, 0, stream>>>(x, Wq, Wk, Wv, Wp, xb, tab);

    gemm_qkv<<<dim3(QS_ / 128, M_ / 128), 256, 0, stream>>>(xb, Wcat, QKV, Vt,
                                                            gain, tab);

    flash<<<dim3(32, H_, B_), 256, 0, stream>>>(QKV, Vt, Y, Opart, Lpart);

    combine<<<2048, 256, 0, stream>>>(Opart, Lpart, Y);

    gemm_proj<<<dim3(D_ / 128, M_ / 128), 256, 0, stream>>>(Y, Wpb, out);
}